// Round 15
// baseline (9714.848 us; speedup 1.0000x reference)
//
#include <hip/hip_runtime.h>
#include <cstdint>

#define S_  128
#define Tt_ 64
#define V_  32000
#define NB_ 256

typedef _Float16 h8 __attribute__((ext_vector_type(8)));
typedef float    f4 __attribute__((ext_vector_type(4)));

#define MFMA16(a,b,c) __builtin_amdgcn_mfma_f32_16x16x32_f16((a),(b),(c),0,0,0)

__device__ __forceinline__ void split8p(const float* __restrict__ p, h8& hi, h8& lo) {
  f4 a = *(const f4*)p;
  f4 b = *(const f4*)(p + 4);
#pragma unroll
  for (int i = 0; i < 4; i++) {
    _Float16 h0 = (_Float16)a[i];
    hi[i] = h0; lo[i] = (_Float16)((a[i] - (float)h0) * 2048.0f);
    _Float16 h1 = (_Float16)b[i];
    hi[i+4] = h1; lo[i+4] = (_Float16)((b[i] - (float)h1) * 2048.0f);
  }
}

// ---- two-level fence-free device barrier (round-12) ----
__device__ __forceinline__ void gsync(unsigned* flags, unsigned* rel, unsigned ep) {
  asm volatile("s_waitcnt vmcnt(0)" ::: "memory");
  __syncthreads();
  int tid = threadIdx.x;
  if (tid == 0) {
    __hip_atomic_store(&flags[blockIdx.x * 4], ep, __ATOMIC_RELAXED,
                       __HIP_MEMORY_SCOPE_AGENT);
  }
  if (blockIdx.x == 0) {
    if (tid < 64) {
      bool done;
      do {
        unsigned m = 0xFFFFFFFFu;
#pragma unroll
        for (int q = 0; q < 4; ++q) {
          unsigned f = __hip_atomic_load(&flags[(tid + q * 64) * 4], __ATOMIC_RELAXED,
                                         __HIP_MEMORY_SCOPE_AGENT);
          m = m < f ? m : f;
        }
        done = (bool)__all(m >= ep);
        if (!done) __builtin_amdgcn_s_sleep(1);
      } while (!done);
      if (tid == 0)
        __hip_atomic_store(rel, ep, __ATOMIC_RELAXED, __HIP_MEMORY_SCOPE_AGENT);
    }
  } else {
    if (tid == 0) {
      while (__hip_atomic_load(rel, __ATOMIC_RELAXED, __HIP_MEMORY_SCOPE_AGENT) < ep)
        __builtin_amdgcn_s_sleep(1);
    }
  }
  __builtin_amdgcn_sched_barrier(0);
  __syncthreads();
  asm volatile("" ::: "memory");
}

__device__ __forceinline__ void store_h_pair(_Float16* __restrict__ oH,
                                             _Float16* __restrict__ oL,
                                             int b, int col0, int lane,
                                             _Float16 hh, _Float16 hl) {
  unsigned hs = (unsigned)__builtin_bit_cast(unsigned short, hh);
  unsigned ls = (unsigned)__builtin_bit_cast(unsigned short, hl);
  unsigned ph = (unsigned)__shfl_xor((int)hs, 32, 64);
  unsigned pl = (unsigned)__shfl_xor((int)ls, 32, 64);
  if (lane < 32) {
    unsigned hw = hs | (ph << 16);
    __hip_atomic_store((unsigned*)(oH + (size_t)b * 1024 + col0), hw,
                       __ATOMIC_RELAXED, __HIP_MEMORY_SCOPE_AGENT);
  } else {
    unsigned lw = pl | (ls << 16);
    __hip_atomic_store((unsigned*)(oL + (size_t)b * 1024 + col0), lw,
                       __ATOMIC_RELAXED, __HIP_MEMORY_SCOPE_AGENT);
  }
}

// ============================ prep kernels ============================

__global__ void k_prep0(float* __restrict__ out,
                        _Float16* __restrict__ seqH, _Float16* __restrict__ seqL,
                        _Float16* __restrict__ ehH, _Float16* __restrict__ ehL,
                        unsigned* __restrict__ encF, unsigned* __restrict__ decF,
                        unsigned* __restrict__ encR, unsigned* __restrict__ decR) {
  int stride = gridDim.x * 256;
  for (unsigned idx = blockIdx.x * 256 + threadIdx.x; idx < 32u * V_; idx += stride) {
    unsigned b = idx / V_, v = idx - b * V_;
    out[(size_t)b * (Tt_ * V_) + v] = 0.0f;
  }
  for (unsigned idx = blockIdx.x * 256 + threadIdx.x; idx < 16384; idx += stride) {
    ((unsigned*)seqH)[idx] = 0u; ((unsigned*)seqL)[idx] = 0u;
    ((unsigned*)ehH)[idx]  = 0u; ((unsigned*)ehL)[idx]  = 0u;
  }
  for (unsigned idx = blockIdx.x * 256 + threadIdx.x; idx < NB_ * 4; idx += stride) {
    encF[idx] = 0u; decF[idx] = 0u;
  }
  if (blockIdx.x == 0 && threadIdx.x < 16) { encR[threadIdx.x] = 0u; decR[threadIdx.x] = 0u; }
}

// decoder weights -> wave-linear tiles: W2[l][blk][w][ks][lane*8]
__global__ void k_dw2(const float* __restrict__ decWih, const float* __restrict__ decWhh,
                      _Float16* __restrict__ W2H, _Float16* __restrict__ W2L) {
  int b = blockIdx.x;            // 8192 = 2 l x 256 blk x 16 w
  int l = b >> 12, rem = b & 4095;
  int blk = rem >> 4, w = rem & 15;
  int t = threadIdx.x;           // 256: 4 ks x 64 lanes
  int ks = t >> 6, lane = t & 63;
  int j16 = lane & 15;
  int grow = (j16 >> 2) * 1024 + blk * 4 + (j16 & 3);
  int kk = w * 128 + ks * 32 + (lane >> 4) * 8;
  const float* src = (kk < 1024)
      ? decWih + ((size_t)l * 4096 + grow) * 1024 + kk
      : decWhh + ((size_t)l * 4096 + grow) * 1024 + (kk - 1024);
  h8 hi, lo; split8p(src, hi, lo);
  size_t d = ((((size_t)l * 256 + blk) * 16 + w) * 4 + ks) * 512 + lane * 8;
  *(h8*)(W2H + d) = hi;
  *(h8*)(W2L + d) = lo;
}

// encoder layer1 weights -> wave-linear tiles: W1e[blk*4+ws][ks(16)][lane*8]
__global__ void k_ew1(const float* __restrict__ encWih, const float* __restrict__ encWhh,
                      _Float16* __restrict__ W1H, _Float16* __restrict__ W1L) {
  int b = blockIdx.x;            // 4096 = 256 blk x 4 ws x 4 ksq
  int blk = b >> 4, rem = b & 15;
  int ws = rem >> 2, ksq = rem & 3;
  int t = threadIdx.x;           // 256: 4 ks-sub x 64 lanes
  int ks = ksq * 4 + (t >> 6), lane = t & 63;
  int j16 = lane & 15;
  int grow = (j16 >> 2) * 1024 + blk * 4 + (j16 & 3);
  int kk = ws * 512 + ks * 32 + (lane >> 4) * 8;
  const float* src = (kk < 1024)
      ? encWih + ((size_t)4096 + grow) * 1024 + kk
      : encWhh + ((size_t)4096 + grow) * 1024 + (kk - 1024);
  h8 hi, lo; split8p(src, hi, lo);
  size_t d = (((size_t)(blk * 4 + ws)) * 16 + ks) * 512 + lane * 8;
  *(h8*)(W1H + d) = hi;
  *(h8*)(W1L + d) = lo;
}

// W_out -> vt tiles: Wo2[vt][ks][lane*8]
__global__ void k_wo2(const float* __restrict__ Wout,
                      _Float16* __restrict__ Wo2H, _Float16* __restrict__ Wo2L) {
  int b = blockIdx.x;            // 16000 = 2000 vt x 8
  int vt = b >> 3, kb = (b & 7) * 4;
  int t = threadIdx.x;
  int ks = kb + (t >> 6), lane = t & 63;
  int vcol = vt * 16 + (lane & 15);
  int kk = ks * 32 + (lane >> 4) * 8;
  h8 hi, lo; split8p(Wout + (size_t)vcol * 1024 + kk, hi, lo);
  size_t d = ((size_t)vt * 32 + ks) * 512 + lane * 8;
  *(h8*)(Wo2H + d) = hi;
  *(h8*)(Wo2L + d) = lo;
}

__global__ void k_emb(const int* __restrict__ itoks, const float* __restrict__ in_emb,
                      _Float16* __restrict__ embH, _Float16* __restrict__ embL) {
  int n = blockIdx.x;                 // 4096
  int b = n & 31, t = n >> 5;
  int tok = itoks[b * S_ + t];
  int k = threadIdx.x * 8;            // 128 thr
  h8 hi, lo;
  split8p(in_emb + (size_t)tok * 1024 + k, hi, lo);
  *(h8*)(embH + (size_t)n * 1024 + k) = hi;
  *(h8*)(embL + (size_t)n * 1024 + k) = lo;
}

// ============================ encoder (cooperative, diagonal 2-layer) ============================

struct EP {
  const float* encWih; const float* encWhh; const float* encbih; const float* encbhh;
  const _Float16 *W1H, *W1L;    // layer1 wave-linear tiles
  const _Float16 *embH, *embL;
  _Float16 *seqH, *seqL;    // 129 slots (layer0 h history)
  _Float16 *ehH, *ehL;      // 129 slots (layer1 h history)
  _Float16 *h0s0H, *h0s0L;  // hist0 slot 0 (cross-kernel)
  _Float16 *h1s0H, *h1s0L;  // hist1 slot 0 (cross-kernel)
  float *cb0, *cb1;
  unsigned* flags; unsigned* rel;
};

__device__ __forceinline__ int wadr(int row, int k) {
  return row * 2048 + ((((k << 1) ^ ((row & 7) << 4))) >> 1);
}

// layer0 weight preload into LDS (512 threads)
__device__ void preload_enc(const float* __restrict__ Wih, const float* __restrict__ Whh,
                            int blk, int tid, _Float16* sWH, _Float16* sWL) {
#pragma unroll 4
  for (int it = 0; it < 16; ++it) {
    int lin = (it * 512 + tid) * 4;
    int j16 = lin >> 11;
    int k   = lin & 2047;
    int g = j16 >> 2, u = j16 & 3;
    int grow = g * 1024 + blk * 4 + u;
    const float* src = (k < 1024) ? (Wih + (size_t)grow * 1024 + k)
                                  : (Whh + (size_t)grow * 1024 + (k - 1024));
    f4 x = *(const f4*)src;
#pragma unroll
    for (int q = 0; q < 4; q++) {
      _Float16 hh = (_Float16)x[q];
      sWH[wadr(j16, k + q)] = hh;
      sWL[wadr(j16, k + q)] = (_Float16)((x[q] - (float)hh) * 2048.0f);
    }
  }
}

// layer0 gate GEMM (waves 0-3, LDS weights), chunked A (4x4)
__device__ void gates_enc(const _Float16* sWH, const _Float16* sWL, float* sScr,
                          const _Float16* __restrict__ xH, const _Float16* __restrict__ xL,
                          const _Float16* __restrict__ hHb, const _Float16* __restrict__ hLb,
                          int tid) {
  int w = tid >> 6, lane = tid & 63;
  int kbase = w * 512;
  bool xp = (w < 2);
  int j16 = lane & 15;
  const _Float16* aH = xp ? xH : (hHb - 1024);
  const _Float16* aL = xp ? xL : (hLb - 1024);
  f4 accH[2] = {}, accM[2] = {};
#pragma unroll
  for (int kc = 0; kc < 4; ++kc) {
    h8 Ah[4][2], Al[4][2];
#pragma unroll
    for (int k4 = 0; k4 < 4; ++k4) {
      int kk = kbase + (kc * 4 + k4) * 32 + (lane >> 4) * 8;
#pragma unroll
      for (int mt = 0; mt < 2; ++mt) {
        int brow = mt * 16 + (lane & 15);
        Ah[k4][mt] = *(const h8*)(aH + (size_t)brow * 1024 + kk);
        Al[k4][mt] = *(const h8*)(aL + (size_t)brow * 1024 + kk);
      }
    }
#pragma unroll
    for (int k4 = 0; k4 < 4; ++k4) {
      int kk = kbase + (kc * 4 + k4) * 32 + (lane >> 4) * 8;
      h8 Bh = *(const h8*)(sWH + wadr(j16, kk));
      h8 Bl = *(const h8*)(sWL + wadr(j16, kk));
#pragma unroll
      for (int mt = 0; mt < 2; ++mt) {
        accH[mt] = MFMA16(Ah[k4][mt], Bh, accH[mt]);
        accM[mt] = MFMA16(Ah[k4][mt], Bl, accM[mt]);
        accM[mt] = MFMA16(Al[k4][mt], Bh, accM[mt]);
      }
    }
  }
#pragma unroll
  for (int mt = 0; mt < 2; ++mt)
#pragma unroll
    for (int r = 0; r < 4; ++r) {
      int b = mt * 16 + (lane >> 4) * 4 + r;
      sScr[w * 544 + b * 17 + j16] = accH[mt][r] + accM[mt][r] * (1.0f / 2048.0f);
    }
}

// layer1 gate GEMM (waves 4-7) — REGISTER-RESIDENT weights
__device__ __forceinline__ void gates_enc1(const h8 (&WrH)[16], const h8 (&WrL)[16],
                           float* sScr,
                           const _Float16* __restrict__ xH, const _Float16* __restrict__ xL,
                           const _Float16* __restrict__ hHb, const _Float16* __restrict__ hLb,
                           int tid) {
  int w = tid >> 6, lane = tid & 63;
  int ws = w - 4;
  int kbase = ws * 512;
  bool xp = (ws < 2);
  int j16 = lane & 15;
  const _Float16* aH = xp ? xH : (hHb - 1024);
  const _Float16* aL = xp ? xL : (hLb - 1024);
  f4 accH[2] = {}, accM[2] = {};
#pragma unroll
  for (int kc = 0; kc < 4; ++kc) {
    h8 Ah[4][2], Al[4][2];
#pragma unroll
    for (int k4 = 0; k4 < 4; ++k4) {
      int kk = kbase + (kc * 4 + k4) * 32 + (lane >> 4) * 8;
#pragma unroll
      for (int mt = 0; mt < 2; ++mt) {
        int brow = mt * 16 + (lane & 15);
        Ah[k4][mt] = *(const h8*)(aH + (size_t)brow * 1024 + kk);
        Al[k4][mt] = *(const h8*)(aL + (size_t)brow * 1024 + kk);
      }
    }
#pragma unroll
    for (int k4 = 0; k4 < 4; ++k4) {
      int ks = kc * 4 + k4;
#pragma unroll
      for (int mt = 0; mt < 2; ++mt) {
        accH[mt] = MFMA16(Ah[k4][mt], WrH[ks], accH[mt]);
        accM[mt] = MFMA16(Ah[k4][mt], WrL[ks], accM[mt]);
        accM[mt] = MFMA16(Al[k4][mt], WrH[ks], accM[mt]);
      }
    }
  }
#pragma unroll
  for (int mt = 0; mt < 2; ++mt)
#pragma unroll
    for (int r = 0; r < 4; ++r) {
      int b = mt * 16 + (lane >> 4) * 4 + r;
      sScr[w * 544 + b * 17 + j16] = accH[mt][r] + accM[mt][r] * (1.0f / 2048.0f);
    }
}

// cell finish (caller must __syncthreads() first)
__device__ void finish_enc(float* sScr, int blk, int tid,
                           const float* __restrict__ bih, const float* __restrict__ bhh,
                           float& c,
                           _Float16* __restrict__ oH, _Float16* __restrict__ oL,
                           _Float16* __restrict__ oH2, _Float16* __restrict__ oL2,
                           float* __restrict__ cOut) {
  if (tid >= 0 && tid < 128) {
    int u = tid >> 5, b = tid & 31, lane = tid & 63;
    float g[4];
#pragma unroll
    for (int gg = 0; gg < 4; ++gg) {
      int j = gg * 4 + u;
      float s = sScr[0 * 544 + b * 17 + j] + sScr[1 * 544 + b * 17 + j]
              + sScr[2 * 544 + b * 17 + j] + sScr[3 * 544 + b * 17 + j];
      int grow = gg * 1024 + blk * 4 + u;
      g[gg] = s + bih[grow] + bhh[grow];
    }
    float ii = 1.0f / (1.0f + expf(-g[0]));
    float ff = 1.0f / (1.0f + expf(-g[1]));
    float gt = tanhf(g[2]);
    float oo = 1.0f / (1.0f + expf(-g[3]));
    c = ff * c + ii * gt;
    float hn = oo * tanhf(c);
    _Float16 hh = (_Float16)hn;
    _Float16 hl = (_Float16)((hn - (float)hh) * 2048.0f);
    int col0 = blk * 4 + (u & 2);
    store_h_pair(oH, oL, b, col0, lane, hh, hl);
    size_t ci = (size_t)b * 1024 + blk * 4 + u;
    if (oH2) { oH2[ci] = hh; oL2[ci] = hl; }
    if (cOut) cOut[ci] = c;
  }
}

__global__ void __launch_bounds__(512, 2) voice_enc(EP P) {
  __shared__ _Float16 sWH[16 * 2048];   // 64 KB (layer0)
  __shared__ _Float16 sWL[16 * 2048];   // 64 KB
  __shared__ float    sScr[8 * 544];    // 17.4 KB
  int blk = blockIdx.x, tid = threadIdx.x;
  int w = tid >> 6, lane = tid & 63;
  float cA = 0.0f, cB = 0.0f;
  unsigned ep = 0;

  // layer1 weights -> registers (waves 4-7 only), loaded once (64 VGPR)
  h8 w1rh[16], w1rl[16];
  if (w >= 4) {
    int ws = w - 4;
    const _Float16* bH = P.W1H + (((size_t)(blk * 4 + ws)) * 16) * 512 + lane * 8;
    const _Float16* bL = P.W1L + (((size_t)(blk * 4 + ws)) * 16) * 512 + lane * 8;
#pragma unroll
    for (int ks = 0; ks < 16; ++ks) {
      w1rh[ks] = *(const h8*)(bH + ks * 512);
      w1rl[ks] = *(const h8*)(bL + ks * 512);
    }
  }

  preload_enc(P.encWih, P.encWhh, blk, tid, sWH, sWL);
  __syncthreads();

  for (int t = 0; t <= 128; ++t) {
    if (w < 4) {
      if (t < 128)
        gates_enc(sWH, sWL, sScr,
                  P.embH + (size_t)t * 32768, P.embL + (size_t)t * 32768,
                  P.seqH + (size_t)t * 32768, P.seqL + (size_t)t * 32768, tid);
    } else {
      if (t >= 1)
        gates_enc1(w1rh, w1rl, sScr,
                   P.seqH + (size_t)t * 32768, P.seqL + (size_t)t * 32768,
                   P.ehH + (size_t)(t - 1) * 32768, P.ehL + (size_t)(t - 1) * 32768,
                   tid);
    }
    __syncthreads();
    if (t < 128 && tid < 256) {
      bool last = (t == 127);
      finish_enc(sScr, blk, tid, P.encbih, P.encbhh, cA,
                 P.seqH + (size_t)(t + 1) * 32768, P.seqL + (size_t)(t + 1) * 32768,
                 last ? P.h0s0H : nullptr, last ? P.h0s0L : nullptr,
                 last ? P.cb0 : nullptr);
    }
    if (t >= 1 && tid >= 256) {
      bool last = (t == 128);
      finish_enc(sScr + 4 * 544, blk, tid - 256, P.encbih + 4096, P.encbhh + 4096, cB,
                 P.ehH + (size_t)t * 32768, P.ehL + (size_t)t * 32768,
                 last ? P.h1s0H : nullptr, last ? P.h1s0L : nullptr,
                 last ? P.cb1 : nullptr);
    }
    gsync(P.flags, P.rel, ++ep);
  }
}

// ============================ decoder (cooperative, 1024 threads, deep-MLP) ============================

struct DP {
  const float* out_emb; const int* target; const int* tfm;
  const _Float16 *dW2H, *dW2L;      // wave-linear tiles
  const float *decbih, *decbhh;
  const _Float16 *Wo2H, *Wo2L;      // vt tiles
  const float* bout;
  _Float16 *hist0H, *hist0L;        // 64 slots
  _Float16 *hist1H, *hist1L;        // 64 slots
  const float *cb0, *cb1;
  unsigned long long* amax;
  unsigned* flags; unsigned* rel;
};

// one LSTM cell GEMM on 16 waves (K=128/wave), FULL preload (24 loads in flight)
template <int XM>
__device__ void dcell16(const _Float16* __restrict__ W2H, const _Float16* __restrict__ W2L,
                        const _Float16* __restrict__ xH, const _Float16* __restrict__ xL,
                        const float* __restrict__ out_emb, int tok0, int tok1,
                        const _Float16* __restrict__ hH, const _Float16* __restrict__ hL,
                        float* sScr, int blk, int tid) {
  int w = tid >> 6, lane = tid & 63;
  int j16 = lane & 15;
  int kbase = w * 128;
  bool xp = (w < 8);
  const _Float16* aH = xp ? xH : (hH - 1024);
  const _Float16* aL = xp ? xL : (hL - 1024);
  const _Float16* wbH = W2H + ((size_t)(blk * 16 + w)) * 2048 + lane * 8;
  const _Float16* wbL = W2L + ((size_t)(blk * 16 + w)) * 2048 + lane * 8;
  h8 Bh[4], Bl[4];
#pragma unroll
  for (int ks = 0; ks < 4; ++ks) {
    Bh[ks] = *(const h8*)(wbH + ks * 512);
    Bl[ks] = *(const h8*)(wbL + ks * 512);
  }
  h8 Ah[4][2], Al[4][2];
#pragma unroll
  for (int ks = 0; ks < 4; ++ks) {
    int kk = kbase + ks * 32 + (lane >> 4) * 8;
#pragma unroll
    for (int mt = 0; mt < 2; ++mt) {
      int brow = mt * 16 + j16;
      if (XM == 2 && xp) {
        int tk = mt ? tok1 : tok0;
        split8p(out_emb + (size_t)tk * 1024 + kk, Ah[ks][mt], Al[ks][mt]);
      } else {
        Ah[ks][mt] = *(const h8*)(aH + (size_t)brow * 1024 + kk);
        Al[ks][mt] = *(const h8*)(aL + (size_t)brow * 1024 + kk);
      }
    }
  }
  f4 accH[2] = {}, accM[2] = {};
#pragma unroll
  for (int ks = 0; ks < 4; ++ks) {
#pragma unroll
    for (int mt = 0; mt < 2; ++mt) {
      accH[mt] = MFMA16(Ah[ks][mt], Bh[ks], accH[mt]);
      accM[mt] = MFMA16(Ah[ks][mt], Bl[ks], accM[mt]);
      accM[mt] = MFMA16(Al[ks][mt], Bh[ks], accM[mt]);
    }
  }
#pragma unroll
  for (int mt = 0; mt < 2; ++mt)
#pragma unroll
    for (int r = 0; r < 4; ++r) {
      int b = mt * 16 + (lane >> 4) * 4 + r;
      sScr[w * 544 + b * 17 + j16] = accH[mt][r] + accM[mt][r] * (1.0f / 2048.0f);
    }
}

__device__ void dcell_finish16(float* sScr, int blk, int tid,
                               const float* __restrict__ bih, const float* __restrict__ bhh,
                               float& c,
                               _Float16* __restrict__ oH, _Float16* __restrict__ oL) {
  __syncthreads();
  if (tid < 128) {
    int u = tid >> 5, b = tid & 31, lanef = tid & 63;
    float g[4];
#pragma unroll
    for (int gg = 0; gg < 4; ++gg) {
      int j = gg * 4 + u;
      float s = 0.0f;
#pragma unroll
      for (int ww = 0; ww < 16; ++ww) s += sScr[ww * 544 + b * 17 + j];
      int growf = gg * 1024 + blk * 4 + u;
      g[gg] = s + bih[growf] + bhh[growf];
    }
    float ii = 1.0f / (1.0f + expf(-g[0]));
    float ff = 1.0f / (1.0f + expf(-g[1]));
    float gt = tanhf(g[2]);
    float oo = 1.0f / (1.0f + expf(-g[3]));
    c = ff * c + ii * gt;
    float hn = oo * tanhf(c);
    _Float16 hh = (_Float16)hn;
    _Float16 hl = (_Float16)((hn - (float)hh) * 2048.0f);
    int col0 = blk * 4 + (u & 2);
    store_h_pair(oH, oL, b, col0, lanef, hh, hl);
  }
}

__global__ void __launch_bounds__(1024, 2) voice_dec(DP P) {
  __shared__ float sScr[16 * 544];      // 34.8 KB (reused by phase C partials)
  int blk = blockIdx.x, tid = threadIdx.x;
  int w = tid >> 6, lane = tid & 63;
  unsigned ep = 0;
  float c0 = 0.0f, c1 = 0.0f;
  if (tid < 128) {
    int u = tid >> 5, b = tid & 31;
    size_t ci = (size_t)b * 1024 + blk * 4 + u;
    c0 = P.cb0[ci];
    c1 = P.cb1[ci];
  }
  const _Float16* W0H = P.dW2H;
  const _Float16* W0L = P.dW2L;
  const _Float16* W1H = P.dW2H + (size_t)8388608;
  const _Float16* W1L = P.dW2L + (size_t)8388608;

  for (int i = 0; i < 63; ++i) {
    _Float16* h0in   = P.hist0H + (size_t)i * 32768;       _Float16* h0inL  = P.hist0L + (size_t)i * 32768;
    _Float16* h0out  = P.hist0H + (size_t)(i + 1) * 32768; _Float16* h0outL = P.hist0L + (size_t)(i + 1) * 32768;
    _Float16* h1in   = P.hist1H + (size_t)i * 32768;       _Float16* h1inL  = P.hist1L + (size_t)i * 32768;
    _Float16* h1out  = P.hist1H + (size_t)(i + 1) * 32768; _Float16* h1outL = P.hist1L + (size_t)(i + 1) * 32768;

    // ---- phase A: layer0 cell (token-rule x) ----
    int tok0 = 0, tok1 = 0;
    if (w < 8) {
      int b0 = lane & 15, b1 = 16 + (lane & 15);
      if (i == 0)              { tok0 = P.target[b0 * Tt_];     tok1 = P.target[b1 * Tt_]; }
      else if (P.tfm[i] > 0)   { tok0 = P.target[b0 * Tt_ + i]; tok1 = P.target[b1 * Tt_ + i]; }
      else {
        unsigned long long a0 = __hip_atomic_load(&P.amax[b0], __ATOMIC_RELAXED, __HIP_MEMORY_SCOPE_AGENT);
        unsigned long long a1 = __hip_atomic_load(&P.amax[b1], __ATOMIC_RELAXED, __HIP_MEMORY_SCOPE_AGENT);
        tok0 = (int)(~(unsigned)a0); tok1 = (int)(~(unsigned)a1);
      }
    }
    dcell16<2>(W0H, W0L, nullptr, nullptr, P.out_emb, tok0, tok1,
               h0in, h0inL, sScr, blk, tid);
    dcell_finish16(sScr, blk, tid, P.decbih, P.decbhh, c0, h0out, h0outL);
    gsync(P.flags, P.rel, ++ep);

    // ---- phase B: layer1 cell ----
    if (blk == 0 && tid < 32)
      __hip_atomic_store(&P.amax[tid], 0ull, __ATOMIC_RELAXED, __HIP_MEMORY_SCOPE_AGENT);
    dcell16<0>(W1H, W1L, h0out, h0outL, nullptr, 0, 0,
               h1in, h1inL, sScr, blk, tid);
    dcell_finish16(sScr, blk, tid, P.decbih + 4096, P.decbhh + 4096, c1, h1out, h1outL);
    gsync(P.flags, P.rel, ++ep);

    // ---- phase C: argmax-only projection (split-K wave pairs, deep preload) ----
    bool needC = (i < 62) && (P.tfm[i + 1] == 0);
    if (needC) {
      int vt = blk * 8 + (w >> 1);
      int kh = w & 1;
      if (vt < 2000) {
        const _Float16* bH = P.Wo2H + ((size_t)vt * 32 + kh * 16) * 512 + lane * 8;
        const _Float16* bL = P.Wo2L + ((size_t)vt * 32 + kh * 16) * 512 + lane * 8;
        int kof = (lane >> 4) * 8;
        f4 accH[2] = {}, accM[2] = {};
#pragma unroll
        for (int kc = 0; kc < 2; ++kc) {
          h8 Bh[8], Bl[8];
#pragma unroll
          for (int k8 = 0; k8 < 8; ++k8) {
            int ks = kc * 8 + k8;
            Bh[k8] = *(const h8*)(bH + ks * 512);
            Bl[k8] = *(const h8*)(bL + ks * 512);
          }
#pragma unroll
          for (int k4c = 0; k4c < 2; ++k4c) {
            h8 Ah[4][2], Al[4][2];
#pragma unroll
            for (int k4 = 0; k4 < 4; ++k4) {
              int ks = kc * 8 + k4c * 4 + k4;
              int kk = (kh * 16 + ks) * 32 + kof;
#pragma unroll
              for (int mt = 0; mt < 2; ++mt) {
                int brow = mt * 16 + (lane & 15);
                Ah[k4][mt] = *(const h8*)(h1out  + (size_t)brow * 1024 + kk);
                Al[k4][mt] = *(const h8*)(h1outL + (size_t)brow * 1024 + kk);
              }
            }
#pragma unroll
            for (int k4 = 0; k4 < 4; ++k4) {
              int ksl = k4c * 4 + k4;
#pragma unroll
              for (int mt = 0; mt < 2; ++mt) {
                accH[mt] = MFMA16(Ah[k4][mt], Bh[ksl], accH[mt]);
                accM[mt] = MFMA16(Ah[k4][mt], Bl[ksl], accM[mt]);
                accM[mt] = MFMA16(Al[k4][mt], Bh[ksl], accM[mt]);
              }
            }
          }
        }
#pragma unroll
        for (int mt = 0; mt < 2; ++mt)
#pragma unroll
          for (int r = 0; r < 4; ++r)
            sScr[w * 512 + (mt * 4 + r) * 64 + lane] =
                accH[mt][r] + accM[mt][r] * (1.0f / 2048.0f);
      }
      __syncthreads();
      if (vt < 2000 && kh == 0) {
        float biasv = P.bout[vt * 16 + (lane & 15)];
#pragma unroll
        for (int mt = 0; mt < 2; ++mt) {
          float vr[4];
#pragma unroll
          for (int r = 0; r < 4; ++r) {
            int idx = (mt * 4 + r) * 64 + lane;
            vr[r] = sScr[w * 512 + idx] + sScr[(w + 1) * 512 + idx] + biasv;
          }
#pragma unroll
          for (int r = 0; r < 4; ++r) {
            float v = vr[r];
            unsigned id = (unsigned)(vt * 16 + (lane & 15));
#pragma unroll
            for (int off = 1; off < 16; off <<= 1) {
              float ov = __shfl_xor(v, off, 64);
              unsigned oi = __shfl_xor(id, off, 64);
              if (ov > v || (ov == v && oi < id)) { v = ov; id = oi; }
            }
            if ((lane & 15) == 0) {
              unsigned kb = __float_as_uint(v);
              kb = (kb & 0x80000000u) ? ~kb : (kb | 0x80000000u);
              unsigned long long key = ((unsigned long long)kb << 32) | (unsigned)(~id);
              int b = mt * 16 + (lane >> 4) * 4 + r;
              unsigned long long cur = __hip_atomic_load(&P.amax[b], __ATOMIC_RELAXED,
                                                         __HIP_MEMORY_SCOPE_AGENT);
              if (cur < key) atomicMax(&P.amax[b], key);
            }
          }
        }
      }
      gsync(P.flags, P.rel, ++ep);
    }
  }
}

// ============================ final batched output GEMM ============================
__global__ void __launch_bounds__(256, 2)
k_out(const _Float16* __restrict__ histH, const _Float16* __restrict__ histL,
      const _Float16* __restrict__ Wo2H, const _Float16* __restrict__ Wo2L,
      const float* __restrict__ bout, float* __restrict__ out) {
  int bid = blockIdx.x;          // 8000 = 500 nb x 16 mg
  int nb = bid / 16, mg = bid % 16;
  int w = threadIdx.x >> 6, lane = threadIdx.x & 63;
  int kof = (lane >> 4) * 8;
  int mt0 = mg * 8 + w * 2;
  f4 accH[2][4] = {}, accM[2][4] = {};
  for (int ks = 0; ks < 32; ++ks) {
    int kk = ks * 32 + kof;
    h8 Ah[2], Al[2];
#pragma unroll
    for (int mti = 0; mti < 2; ++mti) {
      int mt = mt0 + mti;
      if (mt < 126) {
        int m = mt * 16 + (lane & 15);
        int ii = m >> 5, b = m & 31;
        size_t ai = (size_t)(ii + 1) * 32768 + (size_t)b * 1024 + kk;
        Ah[mti] = *(const h8*)(histH + ai);
        Al[mti] = *(const h8*)(histL + ai);
      }
    }
#pragma unroll
    for (int nt = 0; nt < 4; ++nt) {
      size_t bi = ((size_t)(nb * 4 + nt) * 32 + ks) * 512 + lane * 8;
      h8 Bh = *(const h8*)(Wo2H + bi);
      h8 Bl = *(const h8*)(Wo2L + bi);
#pragma unroll
      for (int mti = 0; mti < 2; ++mti) {
        if (mt0 + mti < 126) {
          accH[mti][nt] = MFMA16(Ah[mti], Bh, accH[mti][nt]);
          accM[mti][nt] = MFMA16(Ah[mti], Bl, accM[mti][nt]);
          accM[mti][nt] = MFMA16(Al[mti], Bh, accM[mti][nt]);
        }
      }
    }
  }
#pragma unroll
  for (int mti = 0; mti < 2; ++mti) {
    int mt = mt0 + mti;
    if (mt >= 126) continue;
#pragma unroll
    for (int nt = 0; nt < 4; ++nt) {
      int vcol = (nb * 4 + nt) * 16 + (lane & 15);
      float bias = bout[vcol];
#pragma unroll
      for (int r = 0; r < 4; ++r) {
        int m = mt * 16 + (lane >> 4) * 4 + r;
        int ii = m >> 5, b = m & 31;
        out[(size_t)b * (Tt_ * V_) + (size_t)(ii + 1) * V_ + vcol] =
            accH[mti][nt][r] + accM[mti][nt][r] * (1.0f / 2048.0f) + bias;
      }
    }
  }
}

// ============================ host ============================

extern "C" void kernel_launch(void* const* d_in, const int* in_sizes, int n_in,
                              void* d_out, int out_size, void* d_ws, size_t ws_size,
                              hipStream_t stream) {
  const int*   itoks   = (const int*)d_in[0];
  const int*   target  = (const int*)d_in[1];
  const int*   tfm     = (const int*)d_in[2];
  const float* in_emb  = (const float*)d_in[3];
  const float* out_emb = (const float*)d_in[4];
  const float* encWih  = (const float*)d_in[5];
  const float* encWhh  = (const float*)d_in[6];
  const float* encbih  = (const float*)d_in[7];
  const float* encbhh  = (const float*)d_in[8];
  const float* decWih  = (const float*)d_in[9];
  const float* decWhh  = (const float*)d_in[10];
  const float* decbih  = (const float*)d_in[11];
  const float* decbhh  = (const float*)d_in[12];
  const float* Wout    = (const float*)d_in[13];
  const float* bout    = (const float*)d_in[14];
  float* out = (float*)d_out;

  char* ws = (char*)d_ws;
  size_t off = 0;
  auto alloc = [&](size_t bytes) { void* p = ws + off; off += (bytes + 255) & ~(size_t)255; return p; };
  _Float16* seqH  = (_Float16*)alloc((size_t)129 * 32768 * 2);
  _Float16* seqL  = (_Float16*)alloc((size_t)129 * 32768 * 2);
  _Float16* ehH   = (_Float16*)alloc((size_t)129 * 32768 * 2);
  _Float16* ehL   = (_Float16*)alloc((size_t)129 * 32768 * 2);
  _Float16* embH  = (_Float16*)alloc((size_t)128 * 32768 * 2);
  _Float16* embL  = (_Float16*)alloc((size_t)128 * 32768 * 2);
  _Float16* hist0H = (_Float16*)alloc((size_t)64 * 32768 * 2);
  _Float16* hist0L = (_Float16*)alloc((size_t)64 * 32768 * 2);
  _Float16* hist1H = (_Float16*)alloc((size_t)64 * 32768 * 2);
  _Float16* hist1L = (_Float16*)alloc((size_t)64 * 32768 * 2);
  float*    cb0   = (float*)alloc((size_t)32 * 1024 * 4);
  float*    cb1   = (float*)alloc((size_t)32 * 1024 * 4);
  _Float16* dW2H  = (_Float16*)alloc((size_t)2 * 8388608 * 2);
  _Float16* dW2L  = (_Float16*)alloc((size_t)2 * 8388608 * 2);
  _Float16* W1eH  = (_Float16*)alloc((size_t)1024 * 16 * 512 * 2);
  _Float16* W1eL  = (_Float16*)alloc((size_t)1024 * 16 * 512 * 2);
  _Float16* Wo2H  = (_Float16*)alloc((size_t)2000 * 32 * 512 * 2);
  _Float16* Wo2L  = (_Float16*)alloc((size_t)2000 * 32 * 512 * 2);
  unsigned long long* amax = (unsigned long long*)alloc(32 * 8);
  unsigned* encF = (unsigned*)alloc(NB_ * 4 * 4);
  unsigned* decF = (unsigned*)alloc(NB_ * 4 * 4);
  unsigned* encR = (unsigned*)alloc(256);
  unsigned* decR = (unsigned*)alloc(256);
  if (off > ws_size) return;

  k_prep0<<<1024, 256, 0, stream>>>(out, seqH, seqL, ehH, ehL, encF, decF, encR, decR);
  k_dw2<<<8192, 256, 0, stream>>>(decWih, decWhh, dW2H, dW2L);
  k_ew1<<<4096, 256, 0, stream>>>(encWih, encWhh, W1eH, W1eL);
  k_wo2<<<16000, 256, 0, stream>>>(Wout, Wo2H, Wo2L);
  k_emb<<<4096, 128, 0, stream>>>(itoks, in_emb, embH, embL);

  EP E;
  E.encWih = encWih; E.encWhh = encWhh; E.encbih = encbih; E.encbhh = encbhh;
  E.W1H = W1eH; E.W1L = W1eL;
  E.embH = embH; E.embL = embL;
  E.seqH = seqH; E.seqL = seqL; E.ehH = ehH; E.ehL = ehL;
  E.h0s0H = hist0H; E.h0s0L = hist0L; E.h1s0H = hist1H; E.h1s0L = hist1L;
  E.cb0 = cb0; E.cb1 = cb1; E.flags = encF; E.rel = encR;
  void* eargs[] = { &E };
  hipLaunchCooperativeKernel((void*)voice_enc, dim3(NB_), dim3(512), eargs, 0, stream);

  DP D;
  D.out_emb = out_emb; D.target = target; D.tfm = tfm;
  D.dW2H = dW2H; D.dW2L = dW2L; D.decbih = decbih; D.decbhh = decbhh;
  D.Wo2H = Wo2H; D.Wo2L = Wo2L; D.bout = bout;
  D.hist0H = hist0H; D.hist0L = hist0L; D.hist1H = hist1H; D.hist1L = hist1L;
  D.cb0 = cb0; D.cb1 = cb1; D.amax = amax; D.flags = decF; D.rel = decR;
  void* dargs[] = { &D };
  hipLaunchCooperativeKernel((void*)voice_dec, dim3(NB_), dim3(1024), dargs, 0, stream);

  k_out<<<8000, 256, 0, stream>>>(hist1H, hist1L, Wo2H, Wo2L, bout, out);
}

// Round 16
// 7553.970 us; speedup vs baseline: 1.2861x; 1.2861x over previous
//
#include <hip/hip_runtime.h>
#include <cstdint>

#define S_  128
#define Tt_ 64
#define V_  32000
#define NB_ 256

typedef _Float16 h8 __attribute__((ext_vector_type(8)));
typedef float    f4 __attribute__((ext_vector_type(4)));

#define MFMA16(a,b,c) __builtin_amdgcn_mfma_f32_16x16x32_f16((a),(b),(c),0,0,0)

__device__ __forceinline__ void split8p(const float* __restrict__ p, h8& hi, h8& lo) {
  f4 a = *(const f4*)p;
  f4 b = *(const f4*)(p + 4);
#pragma unroll
  for (int i = 0; i < 4; i++) {
    _Float16 h0 = (_Float16)a[i];
    hi[i] = h0; lo[i] = (_Float16)((a[i] - (float)h0) * 2048.0f);
    _Float16 h1 = (_Float16)b[i];
    hi[i+4] = h1; lo[i+4] = (_Float16)((b[i] - (float)h1) * 2048.0f);
  }
}

// ---- two-level fence-free device barrier (round-12) ----
__device__ __forceinline__ void gsync(unsigned* flags, unsigned* rel, unsigned ep) {
  asm volatile("s_waitcnt vmcnt(0)" ::: "memory");
  __syncthreads();
  int tid = threadIdx.x;
  if (tid == 0) {
    __hip_atomic_store(&flags[blockIdx.x * 4], ep, __ATOMIC_RELAXED,
                       __HIP_MEMORY_SCOPE_AGENT);
  }
  if (blockIdx.x == 0) {
    if (tid < 64) {
      bool done;
      do {
        unsigned m = 0xFFFFFFFFu;
#pragma unroll
        for (int q = 0; q < 4; ++q) {
          unsigned f = __hip_atomic_load(&flags[(tid + q * 64) * 4], __ATOMIC_RELAXED,
                                         __HIP_MEMORY_SCOPE_AGENT);
          m = m < f ? m : f;
        }
        done = (bool)__all(m >= ep);
        if (!done) __builtin_amdgcn_s_sleep(1);
      } while (!done);
      if (tid == 0)
        __hip_atomic_store(rel, ep, __ATOMIC_RELAXED, __HIP_MEMORY_SCOPE_AGENT);
    }
  } else {
    if (tid == 0) {
      while (__hip_atomic_load(rel, __ATOMIC_RELAXED, __HIP_MEMORY_SCOPE_AGENT) < ep)
        __builtin_amdgcn_s_sleep(1);
    }
  }
  __builtin_amdgcn_sched_barrier(0);
  __syncthreads();
  asm volatile("" ::: "memory");
}

__device__ __forceinline__ void store_h_pair(_Float16* __restrict__ oH,
                                             _Float16* __restrict__ oL,
                                             int b, int col0, int lane,
                                             _Float16 hh, _Float16 hl) {
  unsigned hs = (unsigned)__builtin_bit_cast(unsigned short, hh);
  unsigned ls = (unsigned)__builtin_bit_cast(unsigned short, hl);
  unsigned ph = (unsigned)__shfl_xor((int)hs, 32, 64);
  unsigned pl = (unsigned)__shfl_xor((int)ls, 32, 64);
  if (lane < 32) {
    unsigned hw = hs | (ph << 16);
    __hip_atomic_store((unsigned*)(oH + (size_t)b * 1024 + col0), hw,
                       __ATOMIC_RELAXED, __HIP_MEMORY_SCOPE_AGENT);
  } else {
    unsigned lw = pl | (ls << 16);
    __hip_atomic_store((unsigned*)(oL + (size_t)b * 1024 + col0), lw,
                       __ATOMIC_RELAXED, __HIP_MEMORY_SCOPE_AGENT);
  }
}

// ============================ prep kernels ============================

__global__ void k_prep0(float* __restrict__ out,
                        _Float16* __restrict__ seqH, _Float16* __restrict__ seqL,
                        _Float16* __restrict__ ehH, _Float16* __restrict__ ehL,
                        unsigned* __restrict__ encF, unsigned* __restrict__ decF,
                        unsigned* __restrict__ encR, unsigned* __restrict__ decR) {
  int stride = gridDim.x * 256;
  for (unsigned idx = blockIdx.x * 256 + threadIdx.x; idx < 32u * V_; idx += stride) {
    unsigned b = idx / V_, v = idx - b * V_;
    out[(size_t)b * (Tt_ * V_) + v] = 0.0f;
  }
  for (unsigned idx = blockIdx.x * 256 + threadIdx.x; idx < 16384; idx += stride) {
    ((unsigned*)seqH)[idx] = 0u; ((unsigned*)seqL)[idx] = 0u;
    ((unsigned*)ehH)[idx]  = 0u; ((unsigned*)ehL)[idx]  = 0u;
  }
  for (unsigned idx = blockIdx.x * 256 + threadIdx.x; idx < NB_ * 4; idx += stride) {
    encF[idx] = 0u; decF[idx] = 0u;
  }
  if (blockIdx.x == 0 && threadIdx.x < 16) { encR[threadIdx.x] = 0u; decR[threadIdx.x] = 0u; }
}

// decoder weights -> wave-linear tiles: W2[l][blk][w][ks][lane*8]
__global__ void k_dw2(const float* __restrict__ decWih, const float* __restrict__ decWhh,
                      _Float16* __restrict__ W2H, _Float16* __restrict__ W2L) {
  int b = blockIdx.x;            // 8192 = 2 l x 256 blk x 16 w
  int l = b >> 12, rem = b & 4095;
  int blk = rem >> 4, w = rem & 15;
  int t = threadIdx.x;           // 256: 4 ks x 64 lanes
  int ks = t >> 6, lane = t & 63;
  int j16 = lane & 15;
  int grow = (j16 >> 2) * 1024 + blk * 4 + (j16 & 3);
  int kk = w * 128 + ks * 32 + (lane >> 4) * 8;
  const float* src = (kk < 1024)
      ? decWih + ((size_t)l * 4096 + grow) * 1024 + kk
      : decWhh + ((size_t)l * 4096 + grow) * 1024 + (kk - 1024);
  h8 hi, lo; split8p(src, hi, lo);
  size_t d = ((((size_t)l * 256 + blk) * 16 + w) * 4 + ks) * 512 + lane * 8;
  *(h8*)(W2H + d) = hi;
  *(h8*)(W2L + d) = lo;
}

// encoder layer1 weights -> wave-linear tiles: W1e[blk*4+ws][ks(16)][lane*8]
__global__ void k_ew1(const float* __restrict__ encWih, const float* __restrict__ encWhh,
                      _Float16* __restrict__ W1H, _Float16* __restrict__ W1L) {
  int b = blockIdx.x;            // 4096 = 256 blk x 4 ws x 4 ksq
  int blk = b >> 4, rem = b & 15;
  int ws = rem >> 2, ksq = rem & 3;
  int t = threadIdx.x;           // 256: 4 ks-sub x 64 lanes
  int ks = ksq * 4 + (t >> 6), lane = t & 63;
  int j16 = lane & 15;
  int grow = (j16 >> 2) * 1024 + blk * 4 + (j16 & 3);
  int kk = ws * 512 + ks * 32 + (lane >> 4) * 8;
  const float* src = (kk < 1024)
      ? encWih + ((size_t)4096 + grow) * 1024 + kk
      : encWhh + ((size_t)4096 + grow) * 1024 + (kk - 1024);
  h8 hi, lo; split8p(src, hi, lo);
  size_t d = (((size_t)(blk * 4 + ws)) * 16 + ks) * 512 + lane * 8;
  *(h8*)(W1H + d) = hi;
  *(h8*)(W1L + d) = lo;
}

// W_out -> vt tiles: Wo2[vt][ks][lane*8]
__global__ void k_wo2(const float* __restrict__ Wout,
                      _Float16* __restrict__ Wo2H, _Float16* __restrict__ Wo2L) {
  int b = blockIdx.x;            // 16000 = 2000 vt x 8
  int vt = b >> 3, kb = (b & 7) * 4;
  int t = threadIdx.x;
  int ks = kb + (t >> 6), lane = t & 63;
  int vcol = vt * 16 + (lane & 15);
  int kk = ks * 32 + (lane >> 4) * 8;
  h8 hi, lo; split8p(Wout + (size_t)vcol * 1024 + kk, hi, lo);
  size_t d = ((size_t)vt * 32 + ks) * 512 + lane * 8;
  *(h8*)(Wo2H + d) = hi;
  *(h8*)(Wo2L + d) = lo;
}

__global__ void k_emb(const int* __restrict__ itoks, const float* __restrict__ in_emb,
                      _Float16* __restrict__ embH, _Float16* __restrict__ embL) {
  int n = blockIdx.x;                 // 4096
  int b = n & 31, t = n >> 5;
  int tok = itoks[b * S_ + t];
  int k = threadIdx.x * 8;            // 128 thr
  h8 hi, lo;
  split8p(in_emb + (size_t)tok * 1024 + k, hi, lo);
  *(h8*)(embH + (size_t)n * 1024 + k) = hi;
  *(h8*)(embL + (size_t)n * 1024 + k) = lo;
}

// ============================ encoder (cooperative, diagonal 2-layer) ============================

struct EP {
  const float* encWih; const float* encWhh; const float* encbih; const float* encbhh;
  const _Float16 *W1H, *W1L;    // layer1 wave-linear tiles
  const _Float16 *embH, *embL;
  _Float16 *seqH, *seqL;    // 129 slots (layer0 h history)
  _Float16 *ehH, *ehL;      // 129 slots (layer1 h history)
  _Float16 *h0s0H, *h0s0L;  // hist0 slot 0 (cross-kernel)
  _Float16 *h1s0H, *h1s0L;  // hist1 slot 0 (cross-kernel)
  float *cb0, *cb1;
  unsigned* flags; unsigned* rel;
};

__device__ __forceinline__ int wadr(int row, int k) {
  return row * 2048 + ((((k << 1) ^ ((row & 7) << 4))) >> 1);
}

// layer0 weight preload into LDS (512 threads)
__device__ void preload_enc(const float* __restrict__ Wih, const float* __restrict__ Whh,
                            int blk, int tid, _Float16* sWH, _Float16* sWL) {
#pragma unroll 4
  for (int it = 0; it < 16; ++it) {
    int lin = (it * 512 + tid) * 4;
    int j16 = lin >> 11;
    int k   = lin & 2047;
    int g = j16 >> 2, u = j16 & 3;
    int grow = g * 1024 + blk * 4 + u;
    const float* src = (k < 1024) ? (Wih + (size_t)grow * 1024 + k)
                                  : (Whh + (size_t)grow * 1024 + (k - 1024));
    f4 x = *(const f4*)src;
#pragma unroll
    for (int q = 0; q < 4; q++) {
      _Float16 hh = (_Float16)x[q];
      sWH[wadr(j16, k + q)] = hh;
      sWL[wadr(j16, k + q)] = (_Float16)((x[q] - (float)hh) * 2048.0f);
    }
  }
}

// layer0 gate GEMM (waves 0-3, LDS weights), chunked A (4x4)
__device__ void gates_enc(const _Float16* sWH, const _Float16* sWL, float* sScr,
                          const _Float16* __restrict__ xH, const _Float16* __restrict__ xL,
                          const _Float16* __restrict__ hHb, const _Float16* __restrict__ hLb,
                          int tid) {
  int w = tid >> 6, lane = tid & 63;
  int kbase = w * 512;
  bool xp = (w < 2);
  int j16 = lane & 15;
  const _Float16* aH = xp ? xH : (hHb - 1024);
  const _Float16* aL = xp ? xL : (hLb - 1024);
  f4 accH[2] = {}, accM[2] = {};
#pragma unroll
  for (int kc = 0; kc < 4; ++kc) {
    h8 Ah[4][2], Al[4][2];
#pragma unroll
    for (int k4 = 0; k4 < 4; ++k4) {
      int kk = kbase + (kc * 4 + k4) * 32 + (lane >> 4) * 8;
#pragma unroll
      for (int mt = 0; mt < 2; ++mt) {
        int brow = mt * 16 + (lane & 15);
        Ah[k4][mt] = *(const h8*)(aH + (size_t)brow * 1024 + kk);
        Al[k4][mt] = *(const h8*)(aL + (size_t)brow * 1024 + kk);
      }
    }
#pragma unroll
    for (int k4 = 0; k4 < 4; ++k4) {
      int kk = kbase + (kc * 4 + k4) * 32 + (lane >> 4) * 8;
      h8 Bh = *(const h8*)(sWH + wadr(j16, kk));
      h8 Bl = *(const h8*)(sWL + wadr(j16, kk));
#pragma unroll
      for (int mt = 0; mt < 2; ++mt) {
        accH[mt] = MFMA16(Ah[k4][mt], Bh, accH[mt]);
        accM[mt] = MFMA16(Ah[k4][mt], Bl, accM[mt]);
        accM[mt] = MFMA16(Al[k4][mt], Bh, accM[mt]);
      }
    }
  }
#pragma unroll
  for (int mt = 0; mt < 2; ++mt)
#pragma unroll
    for (int r = 0; r < 4; ++r) {
      int b = mt * 16 + (lane >> 4) * 4 + r;
      sScr[w * 544 + b * 17 + j16] = accH[mt][r] + accM[mt][r] * (1.0f / 2048.0f);
    }
}

// layer1 gate GEMM (waves 4-7) — REGISTER-RESIDENT weights
__device__ __forceinline__ void gates_enc1(const h8 (&WrH)[16], const h8 (&WrL)[16],
                           float* sScr,
                           const _Float16* __restrict__ xH, const _Float16* __restrict__ xL,
                           const _Float16* __restrict__ hHb, const _Float16* __restrict__ hLb,
                           int tid) {
  int w = tid >> 6, lane = tid & 63;
  int ws = w - 4;
  int kbase = ws * 512;
  bool xp = (ws < 2);
  int j16 = lane & 15;
  const _Float16* aH = xp ? xH : (hHb - 1024);
  const _Float16* aL = xp ? xL : (hLb - 1024);
  f4 accH[2] = {}, accM[2] = {};
#pragma unroll
  for (int kc = 0; kc < 4; ++kc) {
    h8 Ah[4][2], Al[4][2];
#pragma unroll
    for (int k4 = 0; k4 < 4; ++k4) {
      int kk = kbase + (kc * 4 + k4) * 32 + (lane >> 4) * 8;
#pragma unroll
      for (int mt = 0; mt < 2; ++mt) {
        int brow = mt * 16 + (lane & 15);
        Ah[k4][mt] = *(const h8*)(aH + (size_t)brow * 1024 + kk);
        Al[k4][mt] = *(const h8*)(aL + (size_t)brow * 1024 + kk);
      }
    }
#pragma unroll
    for (int k4 = 0; k4 < 4; ++k4) {
      int ks = kc * 4 + k4;
#pragma unroll
      for (int mt = 0; mt < 2; ++mt) {
        accH[mt] = MFMA16(Ah[k4][mt], WrH[ks], accH[mt]);
        accM[mt] = MFMA16(Ah[k4][mt], WrL[ks], accM[mt]);
        accM[mt] = MFMA16(Al[k4][mt], WrH[ks], accM[mt]);
      }
    }
  }
#pragma unroll
  for (int mt = 0; mt < 2; ++mt)
#pragma unroll
    for (int r = 0; r < 4; ++r) {
      int b = mt * 16 + (lane >> 4) * 4 + r;
      sScr[w * 544 + b * 17 + j16] = accH[mt][r] + accM[mt][r] * (1.0f / 2048.0f);
    }
}

// cell finish (caller must __syncthreads() first)
__device__ void finish_enc(float* sScr, int blk, int tid,
                           const float* __restrict__ bih, const float* __restrict__ bhh,
                           float& c,
                           _Float16* __restrict__ oH, _Float16* __restrict__ oL,
                           _Float16* __restrict__ oH2, _Float16* __restrict__ oL2,
                           float* __restrict__ cOut) {
  if (tid >= 0 && tid < 128) {
    int u = tid >> 5, b = tid & 31, lane = tid & 63;
    float g[4];
#pragma unroll
    for (int gg = 0; gg < 4; ++gg) {
      int j = gg * 4 + u;
      float s = sScr[0 * 544 + b * 17 + j] + sScr[1 * 544 + b * 17 + j]
              + sScr[2 * 544 + b * 17 + j] + sScr[3 * 544 + b * 17 + j];
      int grow = gg * 1024 + blk * 4 + u;
      g[gg] = s + bih[grow] + bhh[grow];
    }
    float ii = 1.0f / (1.0f + expf(-g[0]));
    float ff = 1.0f / (1.0f + expf(-g[1]));
    float gt = tanhf(g[2]);
    float oo = 1.0f / (1.0f + expf(-g[3]));
    c = ff * c + ii * gt;
    float hn = oo * tanhf(c);
    _Float16 hh = (_Float16)hn;
    _Float16 hl = (_Float16)((hn - (float)hh) * 2048.0f);
    int col0 = blk * 4 + (u & 2);
    store_h_pair(oH, oL, b, col0, lane, hh, hl);
    size_t ci = (size_t)b * 1024 + blk * 4 + u;
    if (oH2) { oH2[ci] = hh; oL2[ci] = hl; }
    if (cOut) cOut[ci] = c;
  }
}

__global__ void __launch_bounds__(512, 2) voice_enc(EP P) {
  __shared__ _Float16 sWH[16 * 2048];   // 64 KB (layer0)
  __shared__ _Float16 sWL[16 * 2048];   // 64 KB
  __shared__ float    sScr[8 * 544];    // 17.4 KB
  int blk = blockIdx.x, tid = threadIdx.x;
  int w = tid >> 6, lane = tid & 63;
  float cA = 0.0f, cB = 0.0f;
  unsigned ep = 0;

  // layer1 weights -> registers (waves 4-7 only), loaded once (64 VGPR)
  h8 w1rh[16], w1rl[16];
  if (w >= 4) {
    int ws = w - 4;
    const _Float16* bH = P.W1H + (((size_t)(blk * 4 + ws)) * 16) * 512 + lane * 8;
    const _Float16* bL = P.W1L + (((size_t)(blk * 4 + ws)) * 16) * 512 + lane * 8;
#pragma unroll
    for (int ks = 0; ks < 16; ++ks) {
      w1rh[ks] = *(const h8*)(bH + ks * 512);
      w1rl[ks] = *(const h8*)(bL + ks * 512);
    }
  }

  preload_enc(P.encWih, P.encWhh, blk, tid, sWH, sWL);
  __syncthreads();

  for (int t = 0; t <= 128; ++t) {
    if (w < 4) {
      if (t < 128)
        gates_enc(sWH, sWL, sScr,
                  P.embH + (size_t)t * 32768, P.embL + (size_t)t * 32768,
                  P.seqH + (size_t)t * 32768, P.seqL + (size_t)t * 32768, tid);
    } else {
      if (t >= 1)
        gates_enc1(w1rh, w1rl, sScr,
                   P.seqH + (size_t)t * 32768, P.seqL + (size_t)t * 32768,
                   P.ehH + (size_t)(t - 1) * 32768, P.ehL + (size_t)(t - 1) * 32768,
                   tid);
    }
    __syncthreads();
    if (t < 128 && tid < 256) {
      bool last = (t == 127);
      finish_enc(sScr, blk, tid, P.encbih, P.encbhh, cA,
                 P.seqH + (size_t)(t + 1) * 32768, P.seqL + (size_t)(t + 1) * 32768,
                 last ? P.h0s0H : nullptr, last ? P.h0s0L : nullptr,
                 last ? P.cb0 : nullptr);
    }
    if (t >= 1 && tid >= 256) {
      bool last = (t == 128);
      finish_enc(sScr + 4 * 544, blk, tid - 256, P.encbih + 4096, P.encbhh + 4096, cB,
                 P.ehH + (size_t)t * 32768, P.ehL + (size_t)t * 32768,
                 last ? P.h1s0H : nullptr, last ? P.h1s0L : nullptr,
                 last ? P.cb1 : nullptr);
    }
    gsync(P.flags, P.rel, ++ep);
  }
}

// ============================ decoder (cooperative, 1024 threads, round-12 verbatim) ============================

struct DP {
  const float* out_emb; const int* target; const int* tfm;
  const _Float16 *dW2H, *dW2L;      // wave-linear tiles
  const float *decbih, *decbhh;
  const _Float16 *Wo2H, *Wo2L;      // vt tiles
  const float* bout;
  _Float16 *hist0H, *hist0L;        // 64 slots
  _Float16 *hist1H, *hist1L;        // 64 slots
  const float *cb0, *cb1;
  unsigned long long* amax;
  unsigned* flags; unsigned* rel;
};

// one LSTM cell GEMM on 16 waves (K=128/wave), linear weight tiles, 2-deep A chunks
template <int XM>
__device__ void dcell16(const _Float16* __restrict__ W2H, const _Float16* __restrict__ W2L,
                        const _Float16* __restrict__ xH, const _Float16* __restrict__ xL,
                        const float* __restrict__ out_emb, int tok0, int tok1,
                        const _Float16* __restrict__ hH, const _Float16* __restrict__ hL,
                        float* sScr, int blk, int tid) {
  int w = tid >> 6, lane = tid & 63;
  int j16 = lane & 15;
  int kbase = w * 128;
  bool xp = (w < 8);
  const _Float16* aH = xp ? xH : (hH - 1024);
  const _Float16* aL = xp ? xL : (hL - 1024);
  const _Float16* wbH = W2H + ((size_t)(blk * 16 + w)) * 2048 + lane * 8;
  const _Float16* wbL = W2L + ((size_t)(blk * 16 + w)) * 2048 + lane * 8;
  h8 Bh[4], Bl[4];
#pragma unroll
  for (int ks = 0; ks < 4; ++ks) {
    Bh[ks] = *(const h8*)(wbH + ks * 512);
    Bl[ks] = *(const h8*)(wbL + ks * 512);
  }
  f4 accH[2] = {}, accM[2] = {};
#pragma unroll
  for (int kc = 0; kc < 2; ++kc) {
    h8 Ah[2][2], Al[2][2];
#pragma unroll
    for (int k2 = 0; k2 < 2; ++k2) {
      int kk = kbase + (kc * 2 + k2) * 32 + (lane >> 4) * 8;
#pragma unroll
      for (int mt = 0; mt < 2; ++mt) {
        int brow = mt * 16 + j16;
        if (XM == 2 && xp) {
          int tk = mt ? tok1 : tok0;
          split8p(out_emb + (size_t)tk * 1024 + kk, Ah[k2][mt], Al[k2][mt]);
        } else {
          Ah[k2][mt] = *(const h8*)(aH + (size_t)brow * 1024 + kk);
          Al[k2][mt] = *(const h8*)(aL + (size_t)brow * 1024 + kk);
        }
      }
    }
#pragma unroll
    for (int k2 = 0; k2 < 2; ++k2) {
      int ks = kc * 2 + k2;
#pragma unroll
      for (int mt = 0; mt < 2; ++mt) {
        accH[mt] = MFMA16(Ah[k2][mt], Bh[ks], accH[mt]);
        accM[mt] = MFMA16(Ah[k2][mt], Bl[ks], accM[mt]);
        accM[mt] = MFMA16(Al[k2][mt], Bh[ks], accM[mt]);
      }
    }
  }
#pragma unroll
  for (int mt = 0; mt < 2; ++mt)
#pragma unroll
    for (int r = 0; r < 4; ++r) {
      int b = mt * 16 + (lane >> 4) * 4 + r;
      sScr[w * 544 + b * 17 + j16] = accH[mt][r] + accM[mt][r] * (1.0f / 2048.0f);
    }
}

__device__ void dcell_finish16(float* sScr, int blk, int tid,
                               const float* __restrict__ bih, const float* __restrict__ bhh,
                               float& c,
                               _Float16* __restrict__ oH, _Float16* __restrict__ oL) {
  __syncthreads();
  if (tid < 128) {
    int u = tid >> 5, b = tid & 31, lanef = tid & 63;
    float g[4];
#pragma unroll
    for (int gg = 0; gg < 4; ++gg) {
      int j = gg * 4 + u;
      float s = 0.0f;
#pragma unroll
      for (int ww = 0; ww < 16; ++ww) s += sScr[ww * 544 + b * 17 + j];
      int growf = gg * 1024 + blk * 4 + u;
      g[gg] = s + bih[growf] + bhh[growf];
    }
    float ii = 1.0f / (1.0f + expf(-g[0]));
    float ff = 1.0f / (1.0f + expf(-g[1]));
    float gt = tanhf(g[2]);
    float oo = 1.0f / (1.0f + expf(-g[3]));
    c = ff * c + ii * gt;
    float hn = oo * tanhf(c);
    _Float16 hh = (_Float16)hn;
    _Float16 hl = (_Float16)((hn - (float)hh) * 2048.0f);
    int col0 = blk * 4 + (u & 2);
    store_h_pair(oH, oL, b, col0, lanef, hh, hl);
  }
}

__global__ void __launch_bounds__(1024, 4) voice_dec(DP P) {
  __shared__ float sScr[16 * 544];      // 34.8 KB (reused by phase C partials)
  int blk = blockIdx.x, tid = threadIdx.x;
  int w = tid >> 6, lane = tid & 63;
  unsigned ep = 0;
  float c0 = 0.0f, c1 = 0.0f;
  if (tid < 128) {
    int u = tid >> 5, b = tid & 31;
    size_t ci = (size_t)b * 1024 + blk * 4 + u;
    c0 = P.cb0[ci];
    c1 = P.cb1[ci];
  }
  const _Float16* W0H = P.dW2H;
  const _Float16* W0L = P.dW2L;
  const _Float16* W1H = P.dW2H + (size_t)8388608;
  const _Float16* W1L = P.dW2L + (size_t)8388608;

  for (int i = 0; i < 63; ++i) {
    _Float16* h0in   = P.hist0H + (size_t)i * 32768;       _Float16* h0inL  = P.hist0L + (size_t)i * 32768;
    _Float16* h0out  = P.hist0H + (size_t)(i + 1) * 32768; _Float16* h0outL = P.hist0L + (size_t)(i + 1) * 32768;
    _Float16* h1in   = P.hist1H + (size_t)i * 32768;       _Float16* h1inL  = P.hist1L + (size_t)i * 32768;
    _Float16* h1out  = P.hist1H + (size_t)(i + 1) * 32768; _Float16* h1outL = P.hist1L + (size_t)(i + 1) * 32768;

    // ---- phase A: layer0 cell (token-rule x) ----
    int tok0 = 0, tok1 = 0;
    if (w < 8) {
      int b0 = lane & 15, b1 = 16 + (lane & 15);
      if (i == 0)              { tok0 = P.target[b0 * Tt_];     tok1 = P.target[b1 * Tt_]; }
      else if (P.tfm[i] > 0)   { tok0 = P.target[b0 * Tt_ + i]; tok1 = P.target[b1 * Tt_ + i]; }
      else {
        unsigned long long a0 = __hip_atomic_load(&P.amax[b0], __ATOMIC_RELAXED, __HIP_MEMORY_SCOPE_AGENT);
        unsigned long long a1 = __hip_atomic_load(&P.amax[b1], __ATOMIC_RELAXED, __HIP_MEMORY_SCOPE_AGENT);
        tok0 = (int)(~(unsigned)a0); tok1 = (int)(~(unsigned)a1);
      }
    }
    dcell16<2>(W0H, W0L, nullptr, nullptr, P.out_emb, tok0, tok1,
               h0in, h0inL, sScr, blk, tid);
    dcell_finish16(sScr, blk, tid, P.decbih, P.decbhh, c0, h0out, h0outL);
    gsync(P.flags, P.rel, ++ep);

    // ---- phase B: layer1 cell ----
    if (blk == 0 && tid < 32)
      __hip_atomic_store(&P.amax[tid], 0ull, __ATOMIC_RELAXED, __HIP_MEMORY_SCOPE_AGENT);
    dcell16<0>(W1H, W1L, h0out, h0outL, nullptr, 0, 0,
               h1in, h1inL, sScr, blk, tid);
    dcell_finish16(sScr, blk, tid, P.decbih + 4096, P.decbhh + 4096, c1, h1out, h1outL);
    gsync(P.flags, P.rel, ++ep);

    // ---- phase C: argmax-only projection (split-K wave pairs, 4-deep, round-12) ----
    bool needC = (i < 62) && (P.tfm[i + 1] == 0);
    if (needC) {
      int vt = blk * 8 + (w >> 1);
      int kh = w & 1;
      if (vt < 2000) {
        const _Float16* bH = P.Wo2H + ((size_t)vt * 32 + kh * 16) * 512 + lane * 8;
        const _Float16* bL = P.Wo2L + ((size_t)vt * 32 + kh * 16) * 512 + lane * 8;
        int kof = (lane >> 4) * 8;
        f4 accH[2] = {}, accM[2] = {};
#pragma unroll
        for (int kc = 0; kc < 4; ++kc) {
          h8 Bh[4], Bl[4], Ah[4][2], Al[4][2];
#pragma unroll
          for (int k4 = 0; k4 < 4; ++k4) {
            int ks = kc * 4 + k4;
            Bh[k4] = *(const h8*)(bH + ks * 512);
            Bl[k4] = *(const h8*)(bL + ks * 512);
            int kk = (kh * 16 + ks) * 32 + kof;
#pragma unroll
            for (int mt = 0; mt < 2; ++mt) {
              int brow = mt * 16 + (lane & 15);
              Ah[k4][mt] = *(const h8*)(h1out  + (size_t)brow * 1024 + kk);
              Al[k4][mt] = *(const h8*)(h1outL + (size_t)brow * 1024 + kk);
            }
          }
#pragma unroll
          for (int k4 = 0; k4 < 4; ++k4)
#pragma unroll
            for (int mt = 0; mt < 2; ++mt) {
              accH[mt] = MFMA16(Ah[k4][mt], Bh[k4], accH[mt]);
              accM[mt] = MFMA16(Ah[k4][mt], Bl[k4], accM[mt]);
              accM[mt] = MFMA16(Al[k4][mt], Bh[k4], accM[mt]);
            }
        }
#pragma unroll
        for (int mt = 0; mt < 2; ++mt)
#pragma unroll
          for (int r = 0; r < 4; ++r)
            sScr[w * 512 + (mt * 4 + r) * 64 + lane] =
                accH[mt][r] + accM[mt][r] * (1.0f / 2048.0f);
      }
      __syncthreads();
      if (vt < 2000 && kh == 0) {
        float biasv = P.bout[vt * 16 + (lane & 15)];
#pragma unroll
        for (int mt = 0; mt < 2; ++mt) {
          float vr[4];
#pragma unroll
          for (int r = 0; r < 4; ++r) {
            int idx = (mt * 4 + r) * 64 + lane;
            vr[r] = sScr[w * 512 + idx] + sScr[(w + 1) * 512 + idx] + biasv;
          }
#pragma unroll
          for (int r = 0; r < 4; ++r) {
            float v = vr[r];
            unsigned id = (unsigned)(vt * 16 + (lane & 15));
#pragma unroll
            for (int off = 1; off < 16; off <<= 1) {
              float ov = __shfl_xor(v, off, 64);
              unsigned oi = __shfl_xor(id, off, 64);
              if (ov > v || (ov == v && oi < id)) { v = ov; id = oi; }
            }
            if ((lane & 15) == 0) {
              unsigned kb = __float_as_uint(v);
              kb = (kb & 0x80000000u) ? ~kb : (kb | 0x80000000u);
              unsigned long long key = ((unsigned long long)kb << 32) | (unsigned)(~id);
              int b = mt * 16 + (lane >> 4) * 4 + r;
              unsigned long long cur = __hip_atomic_load(&P.amax[b], __ATOMIC_RELAXED,
                                                         __HIP_MEMORY_SCOPE_AGENT);
              if (cur < key) atomicMax(&P.amax[b], key);
            }
          }
        }
      }
      gsync(P.flags, P.rel, ++ep);
    }
  }
}

// ============================ final batched output GEMM ============================
__global__ void __launch_bounds__(256, 2)
k_out(const _Float16* __restrict__ histH, const _Float16* __restrict__ histL,
      const _Float16* __restrict__ Wo2H, const _Float16* __restrict__ Wo2L,
      const float* __restrict__ bout, float* __restrict__ out) {
  int bid = blockIdx.x;          // 8000 = 500 nb x 16 mg
  int nb = bid / 16, mg = bid % 16;
  int w = threadIdx.x >> 6, lane = threadIdx.x & 63;
  int kof = (lane >> 4) * 8;
  int mt0 = mg * 8 + w * 2;
  f4 accH[2][4] = {}, accM[2][4] = {};
  for (int ks = 0; ks < 32; ++ks) {
    int kk = ks * 32 + kof;
    h8 Ah[2], Al[2];
#pragma unroll
    for (int mti = 0; mti < 2; ++mti) {
      int mt = mt0 + mti;
      if (mt < 126) {
        int m = mt * 16 + (lane & 15);
        int ii = m >> 5, b = m & 31;
        size_t ai = (size_t)(ii + 1) * 32768 + (size_t)b * 1024 + kk;
        Ah[mti] = *(const h8*)(histH + ai);
        Al[mti] = *(const h8*)(histL + ai);
      }
    }
#pragma unroll
    for (int nt = 0; nt < 4; ++nt) {
      size_t bi = ((size_t)(nb * 4 + nt) * 32 + ks) * 512 + lane * 8;
      h8 Bh = *(const h8*)(Wo2H + bi);
      h8 Bl = *(const h8*)(Wo2L + bi);
#pragma unroll
      for (int mti = 0; mti < 2; ++mti) {
        if (mt0 + mti < 126) {
          accH[mti][nt] = MFMA16(Ah[mti], Bh, accH[mti][nt]);
          accM[mti][nt] = MFMA16(Ah[mti], Bl, accM[mti][nt]);
          accM[mti][nt] = MFMA16(Al[mti], Bh, accM[mti][nt]);
        }
      }
    }
  }
#pragma unroll
  for (int mti = 0; mti < 2; ++mti) {
    int mt = mt0 + mti;
    if (mt >= 126) continue;
#pragma unroll
    for (int nt = 0; nt < 4; ++nt) {
      int vcol = (nb * 4 + nt) * 16 + (lane & 15);
      float bias = bout[vcol];
#pragma unroll
      for (int r = 0; r < 4; ++r) {
        int m = mt * 16 + (lane >> 4) * 4 + r;
        int ii = m >> 5, b = m & 31;
        out[(size_t)b * (Tt_ * V_) + (size_t)(ii + 1) * V_ + vcol] =
            accH[mti][nt][r] + accM[mti][nt][r] * (1.0f / 2048.0f) + bias;
      }
    }
  }
}

// ============================ host ============================

extern "C" void kernel_launch(void* const* d_in, const int* in_sizes, int n_in,
                              void* d_out, int out_size, void* d_ws, size_t ws_size,
                              hipStream_t stream) {
  const int*   itoks   = (const int*)d_in[0];
  const int*   target  = (const int*)d_in[1];
  const int*   tfm     = (const int*)d_in[2];
  const float* in_emb  = (const float*)d_in[3];
  const float* out_emb = (const float*)d_in[4];
  const float* encWih  = (const float*)d_in[5];
  const float* encWhh  = (const float*)d_in[6];
  const float* encbih  = (const float*)d_in[7];
  const float* encbhh  = (const float*)d_in[8];
  const float* decWih  = (const float*)d_in[9];
  const float* decWhh  = (const float*)d_in[10];
  const float* decbih  = (const float*)d_in[11];
  const float* decbhh  = (const float*)d_in[12];
  const float* Wout    = (const float*)d_in[13];
  const float* bout    = (const float*)d_in[14];
  float* out = (float*)d_out;

  char* ws = (char*)d_ws;
  size_t off = 0;
  auto alloc = [&](size_t bytes) { void* p = ws + off; off += (bytes + 255) & ~(size_t)255; return p; };
  _Float16* seqH  = (_Float16*)alloc((size_t)129 * 32768 * 2);
  _Float16* seqL  = (_Float16*)alloc((size_t)129 * 32768 * 2);
  _Float16* ehH   = (_Float16*)alloc((size_t)129 * 32768 * 2);
  _Float16* ehL   = (_Float16*)alloc((size_t)129 * 32768 * 2);
  _Float16* embH  = (_Float16*)alloc((size_t)128 * 32768 * 2);
  _Float16* embL  = (_Float16*)alloc((size_t)128 * 32768 * 2);
  _Float16* hist0H = (_Float16*)alloc((size_t)64 * 32768 * 2);
  _Float16* hist0L = (_Float16*)alloc((size_t)64 * 32768 * 2);
  _Float16* hist1H = (_Float16*)alloc((size_t)64 * 32768 * 2);
  _Float16* hist1L = (_Float16*)alloc((size_t)64 * 32768 * 2);
  float*    cb0   = (float*)alloc((size_t)32 * 1024 * 4);
  float*    cb1   = (float*)alloc((size_t)32 * 1024 * 4);
  _Float16* dW2H  = (_Float16*)alloc((size_t)2 * 8388608 * 2);
  _Float16* dW2L  = (_Float16*)alloc((size_t)2 * 8388608 * 2);
  _Float16* W1eH  = (_Float16*)alloc((size_t)1024 * 16 * 512 * 2);
  _Float16* W1eL  = (_Float16*)alloc((size_t)1024 * 16 * 512 * 2);
  _Float16* Wo2H  = (_Float16*)alloc((size_t)2000 * 32 * 512 * 2);
  _Float16* Wo2L  = (_Float16*)alloc((size_t)2000 * 32 * 512 * 2);
  unsigned long long* amax = (unsigned long long*)alloc(32 * 8);
  unsigned* encF = (unsigned*)alloc(NB_ * 4 * 4);
  unsigned* decF = (unsigned*)alloc(NB_ * 4 * 4);
  unsigned* encR = (unsigned*)alloc(256);
  unsigned* decR = (unsigned*)alloc(256);
  if (off > ws_size) return;

  k_prep0<<<1024, 256, 0, stream>>>(out, seqH, seqL, ehH, ehL, encF, decF, encR, decR);
  k_dw2<<<8192, 256, 0, stream>>>(decWih, decWhh, dW2H, dW2L);
  k_ew1<<<4096, 256, 0, stream>>>(encWih, encWhh, W1eH, W1eL);
  k_wo2<<<16000, 256, 0, stream>>>(Wout, Wo2H, Wo2L);
  k_emb<<<4096, 128, 0, stream>>>(itoks, in_emb, embH, embL);

  EP E;
  E.encWih = encWih; E.encWhh = encWhh; E.encbih = encbih; E.encbhh = encbhh;
  E.W1H = W1eH; E.W1L = W1eL;
  E.embH = embH; E.embL = embL;
  E.seqH = seqH; E.seqL = seqL; E.ehH = ehH; E.ehL = ehL;
  E.h0s0H = hist0H; E.h0s0L = hist0L; E.h1s0H = hist1H; E.h1s0L = hist1L;
  E.cb0 = cb0; E.cb1 = cb1; E.flags = encF; E.rel = encR;
  void* eargs[] = { &E };
  hipLaunchCooperativeKernel((void*)voice_enc, dim3(NB_), dim3(512), eargs, 0, stream);

  DP D;
  D.out_emb = out_emb; D.target = target; D.tfm = tfm;
  D.dW2H = dW2H; D.dW2L = dW2L; D.decbih = decbih; D.decbhh = decbhh;
  D.Wo2H = Wo2H; D.Wo2L = Wo2L; D.bout = bout;
  D.hist0H = hist0H; D.hist0L = hist0L; D.hist1H = hist1H; D.hist1L = hist1L;
  D.cb0 = cb0; D.cb1 = cb1; D.amax = amax; D.flags = decF; D.rel = decR;
  void* dargs[] = { &D };
  hipLaunchCooperativeKernel((void*)voice_dec, dim3(NB_), dim3(1024), dargs, 0, stream);

  k_out<<<8000, 256, 0, stream>>>(hist1H, hist1L, Wo2H, Wo2L, bout, out);
}